// Round 10
// baseline (349.222 us; speedup 1.0000x reference)
//
#include <hip/hip_runtime.h>
#include <cstdint>
#include <cstddef>

typedef unsigned short u16t;
typedef __attribute__((ext_vector_type(4))) float f32x4;
typedef __attribute__((ext_vector_type(4))) int i32x4;
typedef __attribute__((ext_vector_type(4))) unsigned int u32x4;
typedef __attribute__((ext_vector_type(8))) __bf16 bf16x8;
typedef __attribute__((ext_vector_type(4))) __bf16 bf16x4;
typedef __attribute__((ext_vector_type(8))) unsigned short u16x8;
typedef __attribute__((ext_vector_type(4))) unsigned short u16x4;

#define INFF __builtin_inff()

__device__ __forceinline__ u16t f2b(float f) {
  union { float f; unsigned u; } x; x.f = f;
  unsigned r = x.u + 0x7FFFu + ((x.u >> 16) & 1u);   // RNE
  return (u16t)(r >> 16);
}

// async global->LDS, 16B per lane. LDS dest = wave-uniform base + lane*16.
__device__ __forceinline__ void gload16(const u16t* g, u16t* l) {
  __builtin_amdgcn_global_load_lds((const __attribute__((address_space(1))) void*)g,
                                   (__attribute__((address_space(3))) void*)l, 16, 0, 0);
}

// ---------------- fused prep: cvt x, cvt ctx, packed cmask bits ----------------
__global__ __launch_bounds__(256) void k_prep(const float* __restrict__ x,
                                              const float* __restrict__ ctx,
                                              u16t* __restrict__ x16,
                                              u16t* __restrict__ ctx16,
                                              const int* __restrict__ cmask,
                                              unsigned int* __restrict__ cmbits) {
  const int bx = blockIdx.x, tid = threadIdx.x;
  if (bx < 2048) {
    int i = bx * 256 + tid;
    f32x4 v = *(const f32x4*)(x + (size_t)i * 4);
    u16x4 o;
    o[0] = f2b(v[0]); o[1] = f2b(v[1]); o[2] = f2b(v[2]); o[3] = f2b(v[3]);
    *(u16x4*)(x16 + (size_t)i * 4) = o;
  } else if (bx < 10240) {
    int i = (bx - 2048) * 256 + tid;
    f32x4 v = *(const f32x4*)(ctx + (size_t)i * 4);
    u16x4 o;
    o[0] = f2b(v[0]); o[1] = f2b(v[1]); o[2] = f2b(v[2]); o[3] = f2b(v[3]);
    *(u16x4*)(ctx16 + (size_t)i * 4) = o;
  } else {
    int b = tid >> 7, wdi = tid & 127;
    const int* cp = cmask + b * 4096 + wdi * 32;
    unsigned int bits = 0;
#pragma unroll
    for (int i = 0; i < 32; ++i) bits |= (cp[i] != 0 ? 1u : 0u) << i;
    cmbits[tid] = bits;
  }
}

// ---------------- fused 3x weight transpose: fp32 (1024 x C) -> bf16 (C x 1024) ----------------
__global__ __launch_bounds__(256) void k_transpose_w3(const float* __restrict__ Wq,
                                                      const float* __restrict__ Wkv,
                                                      const float* __restrict__ Wout,
                                                      u16t* __restrict__ WqT,
                                                      u16t* __restrict__ WkvT,
                                                      u16t* __restrict__ WoutT) {
  __shared__ float tile[64 * 65];
  const int t = threadIdx.x;
  const int bxx = blockIdx.x;
  const float* src; u16t* dst; int C, cb;
  if (bxx < 16)      { src = Wq;   dst = WqT;   C = 1024; cb = bxx * 64; }
  else if (bxx < 48) { src = Wkv;  dst = WkvT;  C = 2048; cb = (bxx - 16) * 64; }
  else               { src = Wout; dst = WoutT; C = 1024; cb = (bxx - 48) * 64; }
  const int rb = blockIdx.y * 64;
#pragma unroll
  for (int it = 0; it < 4; ++it) {
    int c = it * 256 + t;
    int r = c >> 4, ch = c & 15;
    f32x4 v = *(const f32x4*)(src + (size_t)(rb + r) * C + cb + ch * 4);
    float* dp = &tile[r * 65 + ch * 4];
    dp[0] = v[0]; dp[1] = v[1]; dp[2] = v[2]; dp[3] = v[3];
  }
  __syncthreads();
#pragma unroll
  for (int it = 0; it < 2; ++it) {
    int c = it * 256 + t;
    int dr = c >> 3, ch = c & 7;
    u16x8 o;
#pragma unroll
    for (int i = 0; i < 8; ++i) o[i] = f2b(tile[(ch * 8 + i) * 65 + dr]);
    *(u16x8*)(dst + (size_t)(cb + dr) * 1024 + rb + ch * 8) = o;
  }
}

// ---------------- bf16 GEMM: C(MxN) = oscale * A(MxK) @ Bt(NxK)^T ----------------
// MODE 0: bf16 C.  MODE 1: f32 C + bias (NT).  MODE 2: kv-dual (k->C, v->C2=vT).
template <int MODE>
__global__ __launch_bounds__(256) void k_gemm_bt(const u16t* __restrict__ A,
                                                 const u16t* __restrict__ Bt,
                                                 void* __restrict__ C,
                                                 u16t* __restrict__ C2,
                                                 const float* __restrict__ bias,
                                                 float oscale,
                                                 int K, int lda, int ldb, int ldc, int nbx) {
  __shared__ u16t As[128 * 64];
  __shared__ u16t Bs[128 * 64];
  const int tid = threadIdx.x;
  const int lane = tid & 63, wid = tid >> 6;
  const int l16 = lane & 15, lg = lane >> 4;
  const int wr = wid >> 1, wc = wid & 1;
  const int g = blockIdx.x, per = gridDim.x >> 3;
  const int w = (g & 7) * per + (g >> 3);
  const int bx = w % nbx, by = w / nbx;
  const int brow = by * 128, bcol = bx * 128;
  const int sr = lane >> 3, chs = lane & 7;
  f32x4 acc[4][4] = {};

  for (int k0 = 0; k0 < K; k0 += 64) {
#pragma unroll
    for (int it = 0; it < 4; ++it) {
      int row = it * 32 + wid * 8 + sr;
      int ch = chs ^ (row & 7);
      gload16(A + (size_t)(brow + row) * lda + k0 + ch * 8, &As[it * 2048 + wid * 512]);
      gload16(Bt + (size_t)(bcol + row) * ldb + k0 + ch * 8, &Bs[it * 2048 + wid * 512]);
    }
    __syncthreads();
#pragma unroll
    for (int kk = 0; kk < 2; ++kk) {
      bf16x8 af[4], bfv[4];
#pragma unroll
      for (int mi = 0; mi < 4; ++mi) {
        int row = wr * 64 + mi * 16 + l16;
        int kch = (kk * 4 + lg) ^ (row & 7);
        af[mi] = *(const bf16x8*)(&As[row * 64 + kch * 8]);
      }
#pragma unroll
      for (int ni = 0; ni < 4; ++ni) {
        int row = wc * 64 + ni * 16 + l16;
        int kch = (kk * 4 + lg) ^ (row & 7);
        bfv[ni] = *(const bf16x8*)(&Bs[row * 64 + kch * 8]);
      }
#pragma unroll
      for (int mi = 0; mi < 4; ++mi)
#pragma unroll
        for (int ni = 0; ni < 4; ++ni)
          acc[mi][ni] = __builtin_amdgcn_mfma_f32_16x16x32_bf16(af[mi], bfv[ni], acc[mi][ni], 0, 0, 0);
    }
    __syncthreads();
  }

  if (MODE == 2 && bcol >= 1024) {
#pragma unroll
    for (int mi = 0; mi < 4; ++mi) {
#pragma unroll
      for (int ni = 0; ni < 4; ++ni) {
        int vcol = bcol - 1024 + wc * 64 + ni * 16 + l16;
        int h = vcol >> 6, hd = vcol & 63;
        int row0 = brow + wr * 64 + mi * 16 + lg * 4;
        int bb = row0 >> 12, pos = row0 & 4095;
        u16x4 o4;
#pragma unroll
        for (int j = 0; j < 4; ++j) o4[j] = f2b(acc[mi][ni][j]);
        *(u16x4*)(C2 + ((size_t)((bb * 16 + h) * 64 + hd)) * 4096 + pos) = o4;
      }
    }
    return;
  }
#pragma unroll
  for (int mi = 0; mi < 4; ++mi) {
#pragma unroll
    for (int ni = 0; ni < 4; ++ni) {
#pragma unroll
      for (int j = 0; j < 4; ++j) {
        size_t row = (size_t)brow + wr * 64 + mi * 16 + lg * 4 + j;
        int col = bcol + wc * 64 + ni * 16 + l16;
        float v = acc[mi][ni][j] * oscale;
        if (MODE == 1) {
          v += bias[col];
          __builtin_nontemporal_store(v, (float*)C + row * ldc + col);
        } else {
          ((u16t*)C)[row * ldc + col] = f2b(v);
        }
      }
    }
  }
}

// ---------------- fused attention: barrier-free, direct-L2 K/V, coalesced pre ----------------
// Each wave fully independent (16 q-rows). K/V fragments read straight from
// global (L2-resident: 1MB per (b,h), XCD-grouped blocks). LDS = per-wave
// private P-bounce (bf16) + S-bounce (f32). Raw S goes to LDS, then one
// coalesced NT store pass: 2 rows x 512B contiguous per instruction
// (2 segments vs 16 scattered 64B). NO __syncthreads anywhere.
__global__ __launch_bounds__(256) void k_attn(const u16t* __restrict__ k16,
                                              const u16t* __restrict__ vT16,
                                              const u16t* __restrict__ q16,
                                              const unsigned int* __restrict__ cmbits,
                                              const float* __restrict__ dsim,
                                              const float* __restrict__ beta_p,
                                              const int* __restrict__ mask,
                                              float* __restrict__ pre,
                                              u16t* __restrict__ O16) {
  __shared__ u16t Ps[4 * 2048];    // per-wave P [16 q][128 kv] bf16, swizzled (16 KB)
  __shared__ float Sf[4 * 2048];   // per-wave raw S [16 q][128 kv] f32, swizzled (32 KB)

  const int tid = threadIdx.x;
  const int lane = tid & 63, wid = tid >> 6;
  const int l16 = lane & 15, lg = lane >> 4;
  // XCD swizzle: 16 n-blocks sharing (b,h) K/V stay on one XCD
  const int g = blockIdx.x;
  const int w = (g & 7) * 64 + (g >> 3);
  const int nb = w & 15, hb = w >> 4;
  const int h = hb & 15, b = hb >> 4;
  const int qrow0 = nb * 64 + wid * 16;

  bf16x8 aq0, aq1;
  {
    const u16t* qp = q16 + (size_t)(b * 1024 + qrow0 + l16) * 1024 + h * 64 + lg * 8;
    aq0 = *(const bf16x8*)(qp);
    aq1 = *(const bf16x8*)(qp + 32);
  }
  const bool qm = mask[b * 1024 + qrow0 + l16] != 0;

  const float beta = beta_p[0];
  const float ds40 = dsim[b * 4 + 0] * beta, ds41 = dsim[b * 4 + 1] * beta;
  const float ds42 = dsim[b * 4 + 2] * beta, ds43 = dsim[b * 4 + 3] * beta;

  float mrow = -INFF, lsum = 0.f;
  f32x4 o[4] = {};

  const u16t* kbase = k16 + (size_t)b * 4096 * 1024 + (size_t)h * 64;
  const u16t* vbase = vT16 + (size_t)(b * 16 + h) * 64 * 4096;
  float* preb = pre + (size_t)((b * 16 + h) * 1024 + qrow0) * 4096;   // wave q base
  const u32x4* cmw = (const u32x4*)(cmbits + b * 128);                // wave-uniform
  char* Pwb = (char*)&Ps[wid * 2048] + l16 * 256;
  const int pswz = (l16 & 7) << 4;
  char* Swave = (char*)&Sf[wid * 2048];
  char* Swb = Swave + l16 * 512;          // lane's S row base (bytes)

  for (int t = 0; t < 32; ++t) {
    const int kv0 = t * 128;
    const u32x4 Wc = cmw[t];
    const int d = t >> 3;                 // tiles never cross doc boundaries
    const float ds_t = (d & 1) ? ((d & 2) ? ds43 : ds41) : ((d & 2) ? ds42 : ds40);
    const u16t* kt = kbase + (size_t)kv0 * 1024;

    // S^T = K @ Q^T : K fragments direct from global (L2-hit)
    f32x4 s[8];
    __builtin_amdgcn_s_setprio(1);
#pragma unroll
    for (int kb = 0; kb < 8; ++kb) {
      const u16t* kr = kt + (size_t)(kb * 16 + l16) * 1024 + lg * 8;
      bf16x8 bk0 = *(const bf16x8*)(kr);
      bf16x8 bk1 = *(const bf16x8*)(kr + 32);
      f32x4 acc = {0.f, 0.f, 0.f, 0.f};
      acc = __builtin_amdgcn_mfma_f32_16x16x32_bf16(bk0, aq0, acc, 0, 0, 0);
      acc = __builtin_amdgcn_mfma_f32_16x16x32_bf16(bk1, aq1, acc, 0, 0, 0);
      s[kb] = acc;
    }
    __builtin_amdgcn_s_setprio(0);

    // raw S -> LDS bounce; bias from mask bits; row-max
    float tmax = -INFF;
#pragma unroll
    for (int kb = 0; kb < 8; ++kb) {
      *(f32x4*)(Swb + ((kb * 64 + lg * 16) ^ pswz)) = s[kb];
      const unsigned int sh = Wc[kb >> 1] >> ((kb & 1) * 16 + lg * 4);
#pragma unroll
      for (int j = 0; j < 4; ++j) {
        float bias = ((sh >> j) & 1u) ? ds_t : -INFF;
        float t2 = s[kb][j] + bias;
        if (!qm) t2 = 0.f;
        if (t2 == 0.f) t2 = -INFF;     // faithful zero->-inf
        s[kb][j] = t2;
        tmax = fmaxf(tmax, t2);
      }
    }
    tmax = fmaxf(tmax, __shfl_xor(tmax, 16, 64));
    tmax = fmaxf(tmax, __shfl_xor(tmax, 32, 64));
    const float mold = mrow;
    const float mn = fmaxf(mold, tmax);
    const bool nochange = __all(mn == mold);
    mrow = mn;

    // P = exp(t - m) -> per-wave LDS (A-frag layout)
    float psum = 0.f;
#pragma unroll
    for (int kb = 0; kb < 8; ++kb) {
      bf16x4 pb;
#pragma unroll
      for (int j = 0; j < 4; ++j) {
        float p = (mn == -INFF) ? 0.f : __expf(s[kb][j] - mn);
        psum += p;
        pb[j] = (__bf16)p;
      }
      *(bf16x4*)(Pwb + ((kb * 32 + lg * 8) ^ pswz)) = pb;
    }
    asm volatile("" ::: "memory");
    psum += __shfl_xor(psum, 16, 64);
    psum += __shfl_xor(psum, 32, 64);

    if (nochange) {
      lsum += psum;
    } else {
      const float fs = (mn == -INFF) ? 0.f : __expf(mold - mn);
      lsum = lsum * fs + psum;
      float fsj[4];
#pragma unroll
      for (int j = 0; j < 4; ++j) fsj[j] = __shfl(fs, lg * 4 + j, 64);
#pragma unroll
      for (int ni = 0; ni < 4; ++ni)
#pragma unroll
        for (int j = 0; j < 4; ++j) o[ni][j] *= fsj[j];
    }

    // O += P @ V : V fragments direct from global (L2-hit)
    __builtin_amdgcn_s_setprio(1);
#pragma unroll
    for (int kk2 = 0; kk2 < 4; ++kk2) {
      bf16x8 pa = *(const bf16x8*)(Pwb + ((kk2 * 64 + lg * 16) ^ pswz));
#pragma unroll
      for (int ni = 0; ni < 4; ++ni) {
        bf16x8 vb = *(const bf16x8*)(vbase + (size_t)(ni * 16 + l16) * 4096 + kv0 + kk2 * 32 + lg * 8);
        o[ni] = __builtin_amdgcn_mfma_f32_16x16x32_bf16(pa, vb, o[ni], 0, 0, 0);
      }
    }
    __builtin_amdgcn_s_setprio(0);

    // coalesced NT pre-store: instr i covers rows {2i, 2i+1} x 512B contiguous
    asm volatile("" ::: "memory");
    const int rhalf = lane >> 5, c4 = (lane & 31) * 4;
#pragma unroll
    for (int i = 0; i < 8; ++i) {
      const int row2 = i * 2 + rhalf;
      f32x4 v = *(const f32x4*)(Swave + row2 * 512 + ((c4 * 4) ^ ((row2 & 7) << 4)));
      __builtin_nontemporal_store(v, (f32x4*)(preb + (size_t)row2 * 4096 + kv0 + c4));
    }
  }

  float lsj[4];
#pragma unroll
  for (int j = 0; j < 4; ++j) lsj[j] = __shfl(lsum, lg * 4 + j, 64);
#pragma unroll
  for (int ni = 0; ni < 4; ++ni) {
#pragma unroll
    for (int j = 0; j < 4; ++j) {
      size_t row = (size_t)b * 1024 + qrow0 + lg * 4 + j;
      int col = h * 64 + ni * 16 + l16;
      O16[row * 1024 + col] = f2b(o[ni][j] / lsj[j]);
    }
  }
}

extern "C" void kernel_launch(void* const* d_in, const int* in_sizes, int n_in,
                              void* d_out, int out_size, void* d_ws, size_t ws_size,
                              hipStream_t stream) {
  const float* x = (const float*)d_in[0];
  const float* ctx = (const float*)d_in[1];
  const float* dsim = (const float*)d_in[2];
  const int* mask = (const int*)d_in[3];
  const int* cmask = (const int*)d_in[4];
  const float* Wq = (const float*)d_in[5];
  const float* Wkv = (const float*)d_in[6];
  const float* Wout = (const float*)d_in[7];
  const float* bout = (const float*)d_in[8];
  const float* beta = (const float*)d_in[9];

  char* ws = (char*)d_ws;
  u16t* q16 = (u16t*)(ws + (0ull << 20));     //  4 MiB (2048x1024), pre-scaled by d^-0.5
  u16t* k16 = (u16t*)(ws + (4ull << 20));     // 16 MiB (8192x1024) k half, compact
  u16t* vT16 = (u16t*)(ws + (36ull << 20));   // 16 MiB (2,16,64,4096)
  u16t* O16 = (u16t*)(ws + (52ull << 20));    //  4 MiB (2048x1024)
  u16t* x16 = (u16t*)(ws + (56ull << 20));    //  4 MiB
  u16t* ctx16 = (u16t*)(ws + (60ull << 20));  // 16 MiB
  u16t* WqT = (u16t*)(ws + (76ull << 20));    //  2 MiB
  u16t* WkvT = (u16t*)(ws + (78ull << 20));   //  4 MiB
  u16t* WoutT = (u16t*)(ws + (82ull << 20));  //  2 MiB
  unsigned int* cmbits = (unsigned int*)(ws + (84ull << 20)); // 1 KiB

  float* outp = (float*)d_out;
  float* pre = outp + (size_t)2 * 1024 * 1024;

  k_prep<<<10241, 256, 0, stream>>>(x, ctx, x16, ctx16, cmask, cmbits);
  k_transpose_w3<<<dim3(64, 16), 256, 0, stream>>>(Wq, Wkv, Wout, WqT, WkvT, WoutT);

  // q = (x @ Wq) * d^-0.5   (scale fold exact: 2^-5)
  k_gemm_bt<0><<<128, 256, 0, stream>>>(x16, WqT, (void*)q16, nullptr, nullptr, 0.03125f, 1024, 1024, 1024, 1024, 8);
  // kv GEMM: k half -> k16 (compact), v half -> vT16 (transposed per head)
  k_gemm_bt<2><<<1024, 256, 0, stream>>>(ctx16, WkvT, (void*)k16, vT16, nullptr, 1.0f, 1024, 1024, 1024, 1024, 16);
  // fused attention (barrier-free)
  k_attn<<<512, 256, 0, stream>>>(k16, vT16, q16, cmbits, dsim, beta, mask, pre, O16);
  // out = O @ Wout + bout  (f32, NT)
  k_gemm_bt<1><<<128, 256, 0, stream>>>(O16, WoutT, d_out, nullptr, bout, 1.0f, 1024, 1024, 1024, 1024, 8);
}

// Round 11
// 224.658 us; speedup vs baseline: 1.5545x; 1.5545x over previous
//
#include <hip/hip_runtime.h>
#include <cstdint>
#include <cstddef>

typedef unsigned short u16t;
typedef __attribute__((ext_vector_type(4))) float f32x4;
typedef __attribute__((ext_vector_type(4))) int i32x4;
typedef __attribute__((ext_vector_type(4))) unsigned int u32x4;
typedef __attribute__((ext_vector_type(8))) __bf16 bf16x8;
typedef __attribute__((ext_vector_type(4))) __bf16 bf16x4;
typedef __attribute__((ext_vector_type(8))) unsigned short u16x8;
typedef __attribute__((ext_vector_type(4))) unsigned short u16x4;

#define INFF __builtin_inff()

__device__ __forceinline__ u16t f2b(float f) {
  union { float f; unsigned u; } x; x.f = f;
  unsigned r = x.u + 0x7FFFu + ((x.u >> 16) & 1u);   // RNE
  return (u16t)(r >> 16);
}

// async global->LDS, 16B per lane. LDS dest = wave-uniform base + lane*16.
__device__ __forceinline__ void gload16(const u16t* g, u16t* l) {
  __builtin_amdgcn_global_load_lds((const __attribute__((address_space(1))) void*)g,
                                   (__attribute__((address_space(3))) void*)l, 16, 0, 0);
}

// ---------------- fused prep: cvt x, cvt ctx, packed cmask bits ----------------
__global__ __launch_bounds__(256) void k_prep(const float* __restrict__ x,
                                              const float* __restrict__ ctx,
                                              u16t* __restrict__ x16,
                                              u16t* __restrict__ ctx16,
                                              const int* __restrict__ cmask,
                                              unsigned int* __restrict__ cmbits) {
  const int bx = blockIdx.x, tid = threadIdx.x;
  if (bx < 2048) {
    int i = bx * 256 + tid;
    f32x4 v = *(const f32x4*)(x + (size_t)i * 4);
    u16x4 o;
    o[0] = f2b(v[0]); o[1] = f2b(v[1]); o[2] = f2b(v[2]); o[3] = f2b(v[3]);
    *(u16x4*)(x16 + (size_t)i * 4) = o;
  } else if (bx < 10240) {
    int i = (bx - 2048) * 256 + tid;
    f32x4 v = *(const f32x4*)(ctx + (size_t)i * 4);
    u16x4 o;
    o[0] = f2b(v[0]); o[1] = f2b(v[1]); o[2] = f2b(v[2]); o[3] = f2b(v[3]);
    *(u16x4*)(ctx16 + (size_t)i * 4) = o;
  } else {
    int b = tid >> 7, wdi = tid & 127;
    const int* cp = cmask + b * 4096 + wdi * 32;
    unsigned int bits = 0;
#pragma unroll
    for (int i = 0; i < 32; ++i) bits |= (cp[i] != 0 ? 1u : 0u) << i;
    cmbits[tid] = bits;
  }
}

// ---------------- fused 3x weight transpose: fp32 (1024 x C) -> bf16 (C x 1024) ----------------
__global__ __launch_bounds__(256) void k_transpose_w3(const float* __restrict__ Wq,
                                                      const float* __restrict__ Wkv,
                                                      const float* __restrict__ Wout,
                                                      u16t* __restrict__ WqT,
                                                      u16t* __restrict__ WkvT,
                                                      u16t* __restrict__ WoutT) {
  __shared__ float tile[64 * 65];
  const int t = threadIdx.x;
  const int bxx = blockIdx.x;
  const float* src; u16t* dst; int C, cb;
  if (bxx < 16)      { src = Wq;   dst = WqT;   C = 1024; cb = bxx * 64; }
  else if (bxx < 48) { src = Wkv;  dst = WkvT;  C = 2048; cb = (bxx - 16) * 64; }
  else               { src = Wout; dst = WoutT; C = 1024; cb = (bxx - 48) * 64; }
  const int rb = blockIdx.y * 64;
#pragma unroll
  for (int it = 0; it < 4; ++it) {
    int c = it * 256 + t;
    int r = c >> 4, ch = c & 15;
    f32x4 v = *(const f32x4*)(src + (size_t)(rb + r) * C + cb + ch * 4);
    float* dp = &tile[r * 65 + ch * 4];
    dp[0] = v[0]; dp[1] = v[1]; dp[2] = v[2]; dp[3] = v[3];
  }
  __syncthreads();
#pragma unroll
  for (int it = 0; it < 2; ++it) {
    int c = it * 256 + t;
    int dr = c >> 3, ch = c & 7;
    u16x8 o;
#pragma unroll
    for (int i = 0; i < 8; ++i) o[i] = f2b(tile[(ch * 8 + i) * 65 + dr]);
    *(u16x8*)(dst + (size_t)(cb + dr) * 1024 + rb + ch * 8) = o;
  }
}

// ---------------- bf16 GEMM: C(MxN) = oscale * A(MxK) @ Bt(NxK)^T ----------------
// MODE 0: bf16 C.  MODE 1: f32 C + bias (NT).  MODE 2: kv-dual (k->C, v->C2=vT).
template <int MODE>
__global__ __launch_bounds__(256) void k_gemm_bt(const u16t* __restrict__ A,
                                                 const u16t* __restrict__ Bt,
                                                 void* __restrict__ C,
                                                 u16t* __restrict__ C2,
                                                 const float* __restrict__ bias,
                                                 float oscale,
                                                 int K, int lda, int ldb, int ldc, int nbx) {
  __shared__ u16t As[128 * 64];
  __shared__ u16t Bs[128 * 64];
  const int tid = threadIdx.x;
  const int lane = tid & 63, wid = tid >> 6;
  const int l16 = lane & 15, lg = lane >> 4;
  const int wr = wid >> 1, wc = wid & 1;
  const int g = blockIdx.x, per = gridDim.x >> 3;
  const int w = (g & 7) * per + (g >> 3);
  const int bx = w % nbx, by = w / nbx;
  const int brow = by * 128, bcol = bx * 128;
  const int sr = lane >> 3, chs = lane & 7;
  f32x4 acc[4][4] = {};

  for (int k0 = 0; k0 < K; k0 += 64) {
#pragma unroll
    for (int it = 0; it < 4; ++it) {
      int row = it * 32 + wid * 8 + sr;
      int ch = chs ^ (row & 7);
      gload16(A + (size_t)(brow + row) * lda + k0 + ch * 8, &As[it * 2048 + wid * 512]);
      gload16(Bt + (size_t)(bcol + row) * ldb + k0 + ch * 8, &Bs[it * 2048 + wid * 512]);
    }
    __syncthreads();
#pragma unroll
    for (int kk = 0; kk < 2; ++kk) {
      bf16x8 af[4], bfv[4];
#pragma unroll
      for (int mi = 0; mi < 4; ++mi) {
        int row = wr * 64 + mi * 16 + l16;
        int kch = (kk * 4 + lg) ^ (row & 7);
        af[mi] = *(const bf16x8*)(&As[row * 64 + kch * 8]);
      }
#pragma unroll
      for (int ni = 0; ni < 4; ++ni) {
        int row = wc * 64 + ni * 16 + l16;
        int kch = (kk * 4 + lg) ^ (row & 7);
        bfv[ni] = *(const bf16x8*)(&Bs[row * 64 + kch * 8]);
      }
#pragma unroll
      for (int mi = 0; mi < 4; ++mi)
#pragma unroll
        for (int ni = 0; ni < 4; ++ni)
          acc[mi][ni] = __builtin_amdgcn_mfma_f32_16x16x32_bf16(af[mi], bfv[ni], acc[mi][ni], 0, 0, 0);
    }
    __syncthreads();
  }

  if (MODE == 2 && bcol >= 1024) {
#pragma unroll
    for (int mi = 0; mi < 4; ++mi) {
#pragma unroll
      for (int ni = 0; ni < 4; ++ni) {
        int vcol = bcol - 1024 + wc * 64 + ni * 16 + l16;
        int h = vcol >> 6, hd = vcol & 63;
        int row0 = brow + wr * 64 + mi * 16 + lg * 4;
        int bb = row0 >> 12, pos = row0 & 4095;
        u16x4 o4;
#pragma unroll
        for (int j = 0; j < 4; ++j) o4[j] = f2b(acc[mi][ni][j]);
        *(u16x4*)(C2 + ((size_t)((bb * 16 + h) * 64 + hd)) * 4096 + pos) = o4;
      }
    }
    return;
  }
#pragma unroll
  for (int mi = 0; mi < 4; ++mi) {
#pragma unroll
    for (int ni = 0; ni < 4; ++ni) {
#pragma unroll
      for (int j = 0; j < 4; ++j) {
        size_t row = (size_t)brow + wr * 64 + mi * 16 + lg * 4 + j;
        int col = bcol + wc * 64 + ni * 16 + l16;
        float v = acc[mi][ni][j] * oscale;
        if (MODE == 1) {
          v += bias[col];
          __builtin_nontemporal_store(v, (float*)C + row * ldc + col);
        } else {
          ((u16t*)C)[row * ldc + col] = f2b(v);
        }
      }
    }
  }
}

// ---------------- fused attention (swapped-QK^T) -- R8 base + coalesced pre ----------------
// Single-buffered K/V staging (gload_lds), per-wave Sf f32 bounce (32 KB).
// Pre-store pass for tile t-1 issues right after stage(t)'s loads: each store
// instr covers 2 rows x 512B contiguous NT = 2 segments (vs 16x64B scattered).
// Barrier #1: vmcnt(8) (drains stage loads only). Barrier #2: lgkmcnt(0) only
// (never drains the NT store queue). LDS = 16+16+16+32 = 80 KB -> 2 blocks/CU.
__global__ __launch_bounds__(256) void k_attn(const u16t* __restrict__ k16,
                                              const u16t* __restrict__ vT16,
                                              const u16t* __restrict__ q16,
                                              const unsigned int* __restrict__ cmbits,
                                              const float* __restrict__ dsim,
                                              const float* __restrict__ beta_p,
                                              const int* __restrict__ mask,
                                              float* __restrict__ pre,
                                              u16t* __restrict__ O16) {
  __shared__ u16t Ks[128 * 64];    // [kv 128][hd 64] swizzled, 16 KB
  __shared__ u16t Vs[64 * 128];    // [hd 64][kv 128] swizzled, 16 KB
  __shared__ u16t Ps[4 * 2048];    // per-wave P [16 q][128 kv] bf16, 16 KB
  __shared__ float Sf[4 * 2048];   // per-wave raw S [16 q][128 kv] f32, 32 KB

  const int tid = threadIdx.x;
  const int lane = tid & 63, wid = tid >> 6;
  const int l16 = lane & 15, lg = lane >> 4;
  // XCD swizzle: 16 n-blocks sharing (b,h) K/V stay on one XCD
  const int g = blockIdx.x;
  const int w = (g & 7) * 64 + (g >> 3);
  const int nb = w & 15, hb = w >> 4;
  const int h = hb & 15, b = hb >> 4;
  const int qrow0 = nb * 64 + wid * 16;

  bf16x8 aq0, aq1;
  {
    const u16t* qp = q16 + (size_t)(b * 1024 + qrow0 + l16) * 1024 + h * 64 + lg * 8;
    aq0 = *(const bf16x8*)(qp);
    aq1 = *(const bf16x8*)(qp + 32);
  }
  const bool qm = mask[b * 1024 + qrow0 + l16] != 0;

  const float beta = beta_p[0];
  const float ds40 = dsim[b * 4 + 0] * beta, ds41 = dsim[b * 4 + 1] * beta;
  const float ds42 = dsim[b * 4 + 2] * beta, ds43 = dsim[b * 4 + 3] * beta;

  float mrow = -INFF, lsum = 0.f;
  f32x4 o[4] = {};

  const u16t* kbase = k16 + (size_t)b * 4096 * 1024 + (size_t)h * 64;
  const u16t* vbase = vT16 + (size_t)(b * 16 + h) * 64 * 4096;
  float* preb = pre + (size_t)((b * 16 + h) * 1024 + qrow0) * 4096;   // wave q base
  const u32x4* cmw = (const u32x4*)(cmbits + b * 128);                // wave-uniform -> s_load
  char* Pwb = (char*)&Ps[wid * 2048] + l16 * 256;
  const int pswz = (l16 & 7) << 4;
  char* Swave = (char*)&Sf[wid * 2048];
  char* Swb = Swave + l16 * 512;

  auto stage = [&](int kv0s) {
    u16t* Kb = &Ks[wid * 2048];
    u16t* Vb = &Vs[wid * 2048];
#pragma unroll
    for (int it = 0; it < 4; ++it) {
      int row = wid * 32 + it * 8 + (lane >> 3);
      int ch = (lane & 7) ^ (row & 7);
      gload16(kbase + (size_t)(kv0s + row) * 1024 + ch * 8, Kb + it * 512);
    }
#pragma unroll
    for (int it = 0; it < 4; ++it) {
      int row = wid * 16 + it * 4 + (lane >> 4);
      int ch = (lane & 15) ^ (row & 7);
      gload16(vbase + (size_t)row * 4096 + kv0s + ch * 8, Vb + it * 512);
    }
  };

  // coalesced NT store of Sf: instr i covers rows {2i,2i+1} x 512B contiguous
  auto storepass = [&](int kv0p) {
    const int rhalf = lane >> 5, c4 = (lane & 31) * 4;
#pragma unroll
    for (int i = 0; i < 8; ++i) {
      const int row2 = i * 2 + rhalf;
      f32x4 v = *(const f32x4*)(Swave + row2 * 512 + ((c4 * 4) ^ ((row2 & 7) << 4)));
      __builtin_nontemporal_store(v, (f32x4*)(preb + (size_t)row2 * 4096 + kv0p + c4));
    }
  };

  for (int t = 0; t < 32; ++t) {
    const u32x4 Wc = cmw[t];           // scalar (lgkm), drained at barrier #1
    stage(t * 128);                    // 8 vmem loads, FIRST in issue order
    asm volatile("" ::: "memory");
    if (t > 0) storepass((t - 1) * 128);  // 8 NT stores, issued after the loads
    if (t == 0) {
      asm volatile("s_waitcnt vmcnt(0) lgkmcnt(0)" ::: "memory");
    } else {
      // outstanding: [t-1 stores][t loads][t stores] -> vmcnt(8) drains all loads
      asm volatile("s_waitcnt vmcnt(8) lgkmcnt(0)" ::: "memory");
    }
    __builtin_amdgcn_sched_barrier(0);
    __builtin_amdgcn_s_barrier();
    __builtin_amdgcn_sched_barrier(0);

    const int kv0 = t * 128;
    const int d = t >> 3;              // tiles never cross doc boundary
    const float ds_t = (d & 1) ? ((d & 2) ? ds43 : ds41) : ((d & 2) ? ds42 : ds40);

    // S^T = K @ Q^T : lane gets S[q=l16][kv=kb*16+lg*4+j] (already d^-0.5 scaled)
    f32x4 s[8];
#pragma unroll
    for (int kb = 0; kb < 8; ++kb) {
      f32x4 acc = {0.f, 0.f, 0.f, 0.f};
      int row = kb * 16 + l16;
      bf16x8 bk0 = *(const bf16x8*)(&Ks[row * 64 + ((lg ^ (row & 7)) << 3)]);
      bf16x8 bk1 = *(const bf16x8*)(&Ks[row * 64 + (((4 + lg) ^ (row & 7)) << 3)]);
      acc = __builtin_amdgcn_mfma_f32_16x16x32_bf16(bk0, aq0, acc, 0, 0, 0);
      acc = __builtin_amdgcn_mfma_f32_16x16x32_bf16(bk1, aq1, acc, 0, 0, 0);
      s[kb] = acc;
    }

    // raw S -> per-wave LDS bounce; bias from mask bits; row-max
    float tmax = -INFF;
#pragma unroll
    for (int kb = 0; kb < 8; ++kb) {
      *(f32x4*)(Swb + ((kb * 64 + lg * 16) ^ pswz)) = s[kb];
      const unsigned int sh = Wc[kb >> 1] >> ((kb & 1) * 16 + lg * 4);
#pragma unroll
      for (int j = 0; j < 4; ++j) {
        float bias = ((sh >> j) & 1u) ? ds_t : -INFF;
        float t2 = s[kb][j] + bias;
        if (!qm) t2 = 0.f;
        if (t2 == 0.f) t2 = -INFF;     // faithful zero->-inf
        s[kb][j] = t2;
        tmax = fmaxf(tmax, t2);
      }
    }
    tmax = fmaxf(tmax, __shfl_xor(tmax, 16, 64));
    tmax = fmaxf(tmax, __shfl_xor(tmax, 32, 64));
    const float mold = mrow;
    const float mn = fmaxf(mold, tmax);
    const bool nochange = __all(mn == mold);
    mrow = mn;

    // P = exp(t - m) -> per-wave LDS (A-frag layout)
    float psum = 0.f;
#pragma unroll
    for (int kb = 0; kb < 8; ++kb) {
      bf16x4 pb;
#pragma unroll
      for (int j = 0; j < 4; ++j) {
        float p = (mn == -INFF) ? 0.f : __expf(s[kb][j] - mn);
        psum += p;
        pb[j] = (__bf16)p;
      }
      *(bf16x4*)(Pwb + ((kb * 32 + lg * 8) ^ pswz)) = pb;
    }
    asm volatile("" ::: "memory");
    psum += __shfl_xor(psum, 16, 64);
    psum += __shfl_xor(psum, 32, 64);

    if (nochange) {
      lsum += psum;                      // fs == 1 for every lane: skip rescale
    } else {
      const float fs = (mn == -INFF) ? 0.f : __expf(mold - mn);
      lsum = lsum * fs + psum;
      float fsj[4];
#pragma unroll
      for (int j = 0; j < 4; ++j) fsj[j] = __shfl(fs, lg * 4 + j, 64);
#pragma unroll
      for (int ni = 0; ni < 4; ++ni)
#pragma unroll
        for (int j = 0; j < 4; ++j) o[ni][j] *= fsj[j];
    }

    // O += P @ V
#pragma unroll
    for (int kk2 = 0; kk2 < 4; ++kk2) {
      bf16x8 pa = *(const bf16x8*)(Pwb + ((kk2 * 64 + lg * 16) ^ pswz));
#pragma unroll
      for (int ni = 0; ni < 4; ++ni) {
        int vrow = ni * 16 + l16;
        bf16x8 vb = *(const bf16x8*)(&Vs[vrow * 128 + (((kk2 * 4 + lg) ^ (vrow & 7)) << 3)]);
        o[ni] = __builtin_amdgcn_mfma_f32_16x16x32_bf16(pa, vb, o[ni], 0, 0, 0);
      }
    }

    // barrier #2: all waves done READING Ks/Vs before next stage overwrites.
    // lgkmcnt(0) only -- never drains the NT store queue.
    asm volatile("s_waitcnt lgkmcnt(0)" ::: "memory");
    __builtin_amdgcn_sched_barrier(0);
    __builtin_amdgcn_s_barrier();
    __builtin_amdgcn_sched_barrier(0);
  }
  storepass(31 * 128);   // final tile's pre

  float lsj[4];
#pragma unroll
  for (int j = 0; j < 4; ++j) lsj[j] = __shfl(lsum, lg * 4 + j, 64);
#pragma unroll
  for (int ni = 0; ni < 4; ++ni) {
#pragma unroll
    for (int j = 0; j < 4; ++j) {
      size_t row = (size_t)b * 1024 + qrow0 + lg * 4 + j;
      int col = h * 64 + ni * 16 + l16;
      O16[row * 1024 + col] = f2b(o[ni][j] / lsj[j]);
    }
  }
}

extern "C" void kernel_launch(void* const* d_in, const int* in_sizes, int n_in,
                              void* d_out, int out_size, void* d_ws, size_t ws_size,
                              hipStream_t stream) {
  const float* x = (const float*)d_in[0];
  const float* ctx = (const float*)d_in[1];
  const float* dsim = (const float*)d_in[2];
  const int* mask = (const int*)d_in[3];
  const int* cmask = (const int*)d_in[4];
  const float* Wq = (const float*)d_in[5];
  const float* Wkv = (const float*)d_in[6];
  const float* Wout = (const float*)d_in[7];
  const float* bout = (const float*)d_in[8];
  const float* beta = (const float*)d_in[9];

  char* ws = (char*)d_ws;
  u16t* q16 = (u16t*)(ws + (0ull << 20));     //  4 MiB (2048x1024), pre-scaled by d^-0.5
  u16t* k16 = (u16t*)(ws + (4ull << 20));     // 16 MiB (8192x1024) k half, compact
  u16t* vT16 = (u16t*)(ws + (36ull << 20));   // 16 MiB (2,16,64,4096)
  u16t* O16 = (u16t*)(ws + (52ull << 20));    //  4 MiB (2048x1024)
  u16t* x16 = (u16t*)(ws + (56ull << 20));    //  4 MiB
  u16t* ctx16 = (u16t*)(ws + (60ull << 20));  // 16 MiB
  u16t* WqT = (u16t*)(ws + (76ull << 20));    //  2 MiB
  u16t* WkvT = (u16t*)(ws + (78ull << 20));   //  4 MiB
  u16t* WoutT = (u16t*)(ws + (82ull << 20));  //  2 MiB
  unsigned int* cmbits = (unsigned int*)(ws + (84ull << 20)); // 1 KiB

  float* outp = (float*)d_out;
  float* pre = outp + (size_t)2 * 1024 * 1024;

  k_prep<<<10241, 256, 0, stream>>>(x, ctx, x16, ctx16, cmask, cmbits);
  k_transpose_w3<<<dim3(64, 16), 256, 0, stream>>>(Wq, Wkv, Wout, WqT, WkvT, WoutT);

  // q = (x @ Wq) * d^-0.5   (scale fold exact: 2^-5)
  k_gemm_bt<0><<<128, 256, 0, stream>>>(x16, WqT, (void*)q16, nullptr, nullptr, 0.03125f, 1024, 1024, 1024, 1024, 8);
  // kv GEMM: k half -> k16 (compact), v half -> vT16 (transposed per head)
  k_gemm_bt<2><<<1024, 256, 0, stream>>>(ctx16, WkvT, (void*)k16, vT16, nullptr, 1.0f, 1024, 1024, 1024, 1024, 16);
  // fused attention (coalesced pre-stores)
  k_attn<<<512, 256, 0, stream>>>(k16, vT16, q16, cmbits, dsim, beta, mask, pre, O16);
  // out = O @ Wout + bout  (f32, NT)
  k_gemm_bt<1><<<128, 256, 0, stream>>>(O16, WoutT, d_out, nullptr, bout, 1.0f, 1024, 1024, 1024, 1024, 8);
}

// Round 12
// 214.478 us; speedup vs baseline: 1.6282x; 1.0475x over previous
//
#include <hip/hip_runtime.h>
#include <cstdint>
#include <cstddef>

typedef unsigned short u16t;
typedef __attribute__((ext_vector_type(4))) float f32x4;
typedef __attribute__((ext_vector_type(4))) unsigned int u32x4;
typedef __attribute__((ext_vector_type(8))) __bf16 bf16x8;
typedef __attribute__((ext_vector_type(4))) __bf16 bf16x4;
typedef __attribute__((ext_vector_type(8))) unsigned short u16x8;
typedef __attribute__((ext_vector_type(4))) unsigned short u16x4;

#define INFF __builtin_inff()

__device__ __forceinline__ u16t f2b(float f) {
  union { float f; unsigned u; } x; x.f = f;
  unsigned r = x.u + 0x7FFFu + ((x.u >> 16) & 1u);   // RNE
  return (u16t)(r >> 16);
}

// async global->LDS, 16B per lane. LDS dest = wave-uniform base + lane*16.
__device__ __forceinline__ void gload16(const u16t* g, u16t* l) {
  __builtin_amdgcn_global_load_lds((const __attribute__((address_space(1))) void*)g,
                                   (__attribute__((address_space(3))) void*)l, 16, 0, 0);
}

// ---------------- fused prep: cvt x, cvt ctx, cmask bits, 3x weight transpose ----------------
// blocks [0,2048): x cvt; [2048,10240): ctx cvt; 10240: cmask bit-pack;
// [10241,11265): weight transposes (flattened 64 x 16 grid).
__global__ __launch_bounds__(256) void k_prep(const float* __restrict__ x,
                                              const float* __restrict__ ctx,
                                              u16t* __restrict__ x16,
                                              u16t* __restrict__ ctx16,
                                              const int* __restrict__ cmask,
                                              unsigned int* __restrict__ cmbits,
                                              const float* __restrict__ Wq,
                                              const float* __restrict__ Wkv,
                                              const float* __restrict__ Wout,
                                              u16t* __restrict__ WqT,
                                              u16t* __restrict__ WkvT,
                                              u16t* __restrict__ WoutT) {
  const int bx = blockIdx.x, tid = threadIdx.x;
  if (bx < 2048) {
    int i = bx * 256 + tid;
    f32x4 v = *(const f32x4*)(x + (size_t)i * 4);
    u16x4 o;
    o[0] = f2b(v[0]); o[1] = f2b(v[1]); o[2] = f2b(v[2]); o[3] = f2b(v[3]);
    *(u16x4*)(x16 + (size_t)i * 4) = o;
    return;
  } else if (bx < 10240) {
    int i = (bx - 2048) * 256 + tid;
    f32x4 v = *(const f32x4*)(ctx + (size_t)i * 4);
    u16x4 o;
    o[0] = f2b(v[0]); o[1] = f2b(v[1]); o[2] = f2b(v[2]); o[3] = f2b(v[3]);
    *(u16x4*)(ctx16 + (size_t)i * 4) = o;
    return;
  } else if (bx == 10240) {
    int b = tid >> 7, wdi = tid & 127;
    const int* cp = cmask + b * 4096 + wdi * 32;
    unsigned int bits = 0;
#pragma unroll
    for (int i = 0; i < 32; ++i) bits |= (cp[i] != 0 ? 1u : 0u) << i;
    cmbits[tid] = bits;
    return;
  }
  // weight transpose: id = bx-10241, bxx = id&63 (matrix+col block), by = id>>6 (row block)
  __shared__ float tile[64 * 65];
  const int id = bx - 10241;
  const int bxx = id & 63;
  const float* src; u16t* dst; int C, cb;
  if (bxx < 16)      { src = Wq;   dst = WqT;   C = 1024; cb = bxx * 64; }
  else if (bxx < 48) { src = Wkv;  dst = WkvT;  C = 2048; cb = (bxx - 16) * 64; }
  else               { src = Wout; dst = WoutT; C = 1024; cb = (bxx - 48) * 64; }
  const int rb = (id >> 6) * 64;
#pragma unroll
  for (int it = 0; it < 4; ++it) {
    int c = it * 256 + tid;
    int r = c >> 4, ch = c & 15;
    f32x4 v = *(const f32x4*)(src + (size_t)(rb + r) * C + cb + ch * 4);
    float* dp = &tile[r * 65 + ch * 4];
    dp[0] = v[0]; dp[1] = v[1]; dp[2] = v[2]; dp[3] = v[3];
  }
  __syncthreads();
#pragma unroll
  for (int it = 0; it < 2; ++it) {
    int c = it * 256 + tid;
    int dr = c >> 3, ch = c & 7;
    u16x8 o;
#pragma unroll
    for (int i = 0; i < 8; ++i) o[i] = f2b(tile[(ch * 8 + i) * 65 + dr]);
    *(u16x8*)(dst + (size_t)(cb + dr) * 1024 + rb + ch * 8) = o;
  }
}

// ---------------- GEMM core: C(MxN) = oscale * A(MxK) @ Bt(NxK)^T ----------------
// MODE 0: bf16 C.  MODE 1: f32 C + bias (NT).  MODE 2: kv-dual (k->C direct;
// v-half -> C2=vT via LDS-bounce coalesced transposed store).
template <int MODE>
__device__ __forceinline__ void gemm_body(int g, int per, int nbx,
                                          const u16t* __restrict__ A,
                                          const u16t* __restrict__ Bt,
                                          void* __restrict__ C,
                                          u16t* __restrict__ C2,
                                          const float* __restrict__ bias,
                                          float oscale,
                                          int K, int lda, int ldb, int ldc,
                                          u16t* As, u16t* Bs) {
  const int tid = threadIdx.x;
  const int lane = tid & 63, wid = tid >> 6;
  const int l16 = lane & 15, lg = lane >> 4;
  const int wr = wid >> 1, wc = wid & 1;
  const int w = (g & 7) * per + (g >> 3);       // XCD-aware bijective swizzle
  const int bx = w % nbx, by = w / nbx;
  const int brow = by * 128, bcol = bx * 128;
  const int sr = lane >> 3, chs = lane & 7;
  f32x4 acc[4][4] = {};

  for (int k0 = 0; k0 < K; k0 += 64) {
#pragma unroll
    for (int it = 0; it < 4; ++it) {
      int row = it * 32 + wid * 8 + sr;
      int ch = chs ^ (row & 7);
      gload16(A + (size_t)(brow + row) * lda + k0 + ch * 8, &As[it * 2048 + wid * 512]);
      gload16(Bt + (size_t)(bcol + row) * ldb + k0 + ch * 8, &Bs[it * 2048 + wid * 512]);
    }
    __syncthreads();
#pragma unroll
    for (int kk = 0; kk < 2; ++kk) {
      bf16x8 af[4], bfv[4];
#pragma unroll
      for (int mi = 0; mi < 4; ++mi) {
        int row = wr * 64 + mi * 16 + l16;
        int kch = (kk * 4 + lg) ^ (row & 7);
        af[mi] = *(const bf16x8*)(&As[row * 64 + kch * 8]);
      }
#pragma unroll
      for (int ni = 0; ni < 4; ++ni) {
        int row = wc * 64 + ni * 16 + l16;
        int kch = (kk * 4 + lg) ^ (row & 7);
        bfv[ni] = *(const bf16x8*)(&Bs[row * 64 + kch * 8]);
      }
#pragma unroll
      for (int mi = 0; mi < 4; ++mi)
#pragma unroll
        for (int ni = 0; ni < 4; ++ni)
          acc[mi][ni] = __builtin_amdgcn_mfma_f32_16x16x32_bf16(af[mi], bfv[ni], acc[mi][ni], 0, 0, 0);
    }
    __syncthreads();
  }

  if (MODE == 2 && bcol >= 1024) {
    // v half: bounce through LDS as [vcol 128][pos 128] bf16 (XOR-swizzled),
    // then store vT rows 256B-contiguous (4 segments/instr vs 16 scattered 8B).
    u16t* L = As;  // As+Bs contiguous 32 KB, free after K-loop
#pragma unroll
    for (int ni = 0; ni < 4; ++ni) {
      int vcol = wc * 64 + ni * 16 + l16;
      int swz = (vcol & 7) << 4;
#pragma unroll
      for (int mi = 0; mi < 4; ++mi) {
        int pos0 = wr * 64 + mi * 16 + lg * 4;
        u16x4 pb;
#pragma unroll
        for (int j = 0; j < 4; ++j) pb[j] = f2b(acc[mi][ni][j]);
        *(u16x4*)((char*)L + vcol * 256 + ((pos0 * 2) ^ swz)) = pb;
      }
    }
    __syncthreads();
    const int bb = brow >> 12, basepos = brow & 4095;
#pragma unroll
    for (int p = 0; p < 8; ++p) {
      int o = p * 4096 + tid * 16;
      int r = o >> 8, bix = o & 255;
      u16x8 v = *(const u16x8*)((char*)L + r * 256 + (bix ^ ((r & 7) << 4)));
      int gv = bcol - 1024 + r, h = gv >> 6, hd = gv & 63;
      *(u16x8*)(C2 + ((size_t)((bb * 16 + h) * 64 + hd)) * 4096 + basepos + (bix >> 1)) = v;
    }
    __syncthreads();   // protect L before any later reuse
    return;
  }
#pragma unroll
  for (int mi = 0; mi < 4; ++mi) {
#pragma unroll
    for (int ni = 0; ni < 4; ++ni) {
#pragma unroll
      for (int j = 0; j < 4; ++j) {
        size_t row = (size_t)brow + wr * 64 + mi * 16 + lg * 4 + j;
        int col = bcol + wc * 64 + ni * 16 + l16;
        float v = acc[mi][ni][j] * oscale;
        if (MODE == 1) {
          v += bias[col];
          __builtin_nontemporal_store(v, (float*)C + row * ldc + col);
        } else {
          ((u16t*)C)[row * ldc + col] = f2b(v);
        }
      }
    }
  }
}

// combined q + kv GEMM: blocks [0,1024) = kv (MODE2), [1024,1152) = q (MODE0).
__global__ __launch_bounds__(256) void k_gemm_qkv(const u16t* __restrict__ x16,
                                                  const u16t* __restrict__ WqT,
                                                  u16t* __restrict__ q16,
                                                  const u16t* __restrict__ ctx16,
                                                  const u16t* __restrict__ WkvT,
                                                  u16t* __restrict__ k16,
                                                  u16t* __restrict__ vT16) {
  __shared__ u16t smem[2 * 128 * 64];
  u16t* As = smem;
  u16t* Bs = smem + 128 * 64;
  if (blockIdx.x < 1024)
    gemm_body<2>(blockIdx.x, 128, 16, ctx16, WkvT, (void*)k16, vT16, nullptr, 1.0f,
                 1024, 1024, 1024, 1024, As, Bs);
  else
    gemm_body<0>(blockIdx.x - 1024, 16, 8, x16, WqT, (void*)q16, nullptr, nullptr, 0.03125f,
                 1024, 1024, 1024, 1024, As, Bs);
}

// out = O @ Wout + bout (f32, NT)
__global__ __launch_bounds__(256) void k_gemm_out(const u16t* __restrict__ O16,
                                                  const u16t* __restrict__ WoutT,
                                                  float* __restrict__ out,
                                                  const float* __restrict__ bout) {
  __shared__ u16t smem[2 * 128 * 64];
  gemm_body<1>(blockIdx.x, 16, 8, O16, WoutT, (void*)out, nullptr, bout, 1.0f,
               1024, 1024, 1024, 1024, smem, smem + 128 * 64);
}

// ---------------- fused attention (R11, unchanged) ----------------
__global__ __launch_bounds__(256) void k_attn(const u16t* __restrict__ k16,
                                              const u16t* __restrict__ vT16,
                                              const u16t* __restrict__ q16,
                                              const unsigned int* __restrict__ cmbits,
                                              const float* __restrict__ dsim,
                                              const float* __restrict__ beta_p,
                                              const int* __restrict__ mask,
                                              float* __restrict__ pre,
                                              u16t* __restrict__ O16) {
  __shared__ u16t Ks[128 * 64];    // [kv 128][hd 64] swizzled, 16 KB
  __shared__ u16t Vs[64 * 128];    // [hd 64][kv 128] swizzled, 16 KB
  __shared__ u16t Ps[4 * 2048];    // per-wave P [16 q][128 kv] bf16, 16 KB
  __shared__ float Sf[4 * 2048];   // per-wave raw S [16 q][128 kv] f32, 32 KB

  const int tid = threadIdx.x;
  const int lane = tid & 63, wid = tid >> 6;
  const int l16 = lane & 15, lg = lane >> 4;
  const int g = blockIdx.x;
  const int w = (g & 7) * 64 + (g >> 3);
  const int nb = w & 15, hb = w >> 4;
  const int h = hb & 15, b = hb >> 4;
  const int qrow0 = nb * 64 + wid * 16;

  bf16x8 aq0, aq1;
  {
    const u16t* qp = q16 + (size_t)(b * 1024 + qrow0 + l16) * 1024 + h * 64 + lg * 8;
    aq0 = *(const bf16x8*)(qp);
    aq1 = *(const bf16x8*)(qp + 32);
  }
  const bool qm = mask[b * 1024 + qrow0 + l16] != 0;

  const float beta = beta_p[0];
  const float ds40 = dsim[b * 4 + 0] * beta, ds41 = dsim[b * 4 + 1] * beta;
  const float ds42 = dsim[b * 4 + 2] * beta, ds43 = dsim[b * 4 + 3] * beta;

  float mrow = -INFF, lsum = 0.f;
  f32x4 o[4] = {};

  const u16t* kbase = k16 + (size_t)b * 4096 * 1024 + (size_t)h * 64;
  const u16t* vbase = vT16 + (size_t)(b * 16 + h) * 64 * 4096;
  float* preb = pre + (size_t)((b * 16 + h) * 1024 + qrow0) * 4096;
  const u32x4* cmw = (const u32x4*)(cmbits + b * 128);
  char* Pwb = (char*)&Ps[wid * 2048] + l16 * 256;
  const int pswz = (l16 & 7) << 4;
  char* Swave = (char*)&Sf[wid * 2048];
  char* Swb = Swave + l16 * 512;

  auto stage = [&](int kv0s) {
    u16t* Kb = &Ks[wid * 2048];
    u16t* Vb = &Vs[wid * 2048];
#pragma unroll
    for (int it = 0; it < 4; ++it) {
      int row = wid * 32 + it * 8 + (lane >> 3);
      int ch = (lane & 7) ^ (row & 7);
      gload16(kbase + (size_t)(kv0s + row) * 1024 + ch * 8, Kb + it * 512);
    }
#pragma unroll
    for (int it = 0; it < 4; ++it) {
      int row = wid * 16 + it * 4 + (lane >> 4);
      int ch = (lane & 15) ^ (row & 7);
      gload16(vbase + (size_t)row * 4096 + kv0s + ch * 8, Vb + it * 512);
    }
  };

  auto storepass = [&](int kv0p) {
    const int rhalf = lane >> 5, c4 = (lane & 31) * 4;
#pragma unroll
    for (int i = 0; i < 8; ++i) {
      const int row2 = i * 2 + rhalf;
      f32x4 v = *(const f32x4*)(Swave + row2 * 512 + ((c4 * 4) ^ ((row2 & 7) << 4)));
      __builtin_nontemporal_store(v, (f32x4*)(preb + (size_t)row2 * 4096 + kv0p + c4));
    }
  };

  for (int t = 0; t < 32; ++t) {
    const u32x4 Wc = cmw[t];
    stage(t * 128);
    asm volatile("" ::: "memory");
    if (t > 0) storepass((t - 1) * 128);
    if (t == 0) {
      asm volatile("s_waitcnt vmcnt(0) lgkmcnt(0)" ::: "memory");
    } else {
      asm volatile("s_waitcnt vmcnt(8) lgkmcnt(0)" ::: "memory");
    }
    __builtin_amdgcn_sched_barrier(0);
    __builtin_amdgcn_s_barrier();
    __builtin_amdgcn_sched_barrier(0);

    const int kv0 = t * 128;
    const int d = t >> 3;
    const float ds_t = (d & 1) ? ((d & 2) ? ds43 : ds41) : ((d & 2) ? ds42 : ds40);

    f32x4 s[8];
#pragma unroll
    for (int kb = 0; kb < 8; ++kb) {
      f32x4 acc = {0.f, 0.f, 0.f, 0.f};
      int row = kb * 16 + l16;
      bf16x8 bk0 = *(const bf16x8*)(&Ks[row * 64 + ((lg ^ (row & 7)) << 3)]);
      bf16x8 bk1 = *(const bf16x8*)(&Ks[row * 64 + (((4 + lg) ^ (row & 7)) << 3)]);
      acc = __builtin_amdgcn_mfma_f32_16x16x32_bf16(bk0, aq0, acc, 0, 0, 0);
      acc = __builtin_amdgcn_mfma_f32_16x16x32_bf16(bk1, aq1, acc, 0, 0, 0);
      s[kb] = acc;
    }

    float tmax = -INFF;
#pragma unroll
    for (int kb = 0; kb < 8; ++kb) {
      *(f32x4*)(Swb + ((kb * 64 + lg * 16) ^ pswz)) = s[kb];
      const unsigned int sh = Wc[kb >> 1] >> ((kb & 1) * 16 + lg * 4);
#pragma unroll
      for (int j = 0; j < 4; ++j) {
        float bias = ((sh >> j) & 1u) ? ds_t : -INFF;
        float t2 = s[kb][j] + bias;
        if (!qm) t2 = 0.f;
        if (t2 == 0.f) t2 = -INFF;
        s[kb][j] = t2;
        tmax = fmaxf(tmax, t2);
      }
    }
    tmax = fmaxf(tmax, __shfl_xor(tmax, 16, 64));
    tmax = fmaxf(tmax, __shfl_xor(tmax, 32, 64));
    const float mold = mrow;
    const float mn = fmaxf(mold, tmax);
    const bool nochange = __all(mn == mold);
    mrow = mn;

    float psum = 0.f;
#pragma unroll
    for (int kb = 0; kb < 8; ++kb) {
      bf16x4 pb;
#pragma unroll
      for (int j = 0; j < 4; ++j) {
        float p = (mn == -INFF) ? 0.f : __expf(s[kb][j] - mn);
        psum += p;
        pb[j] = (__bf16)p;
      }
      *(bf16x4*)(Pwb + ((kb * 32 + lg * 8) ^ pswz)) = pb;
    }
    asm volatile("" ::: "memory");
    psum += __shfl_xor(psum, 16, 64);
    psum += __shfl_xor(psum, 32, 64);

    if (nochange) {
      lsum += psum;
    } else {
      const float fs = (mn == -INFF) ? 0.f : __expf(mold - mn);
      lsum = lsum * fs + psum;
      float fsj[4];
#pragma unroll
      for (int j = 0; j < 4; ++j) fsj[j] = __shfl(fs, lg * 4 + j, 64);
#pragma unroll
      for (int ni = 0; ni < 4; ++ni)
#pragma unroll
        for (int j = 0; j < 4; ++j) o[ni][j] *= fsj[j];
    }

#pragma unroll
    for (int kk2 = 0; kk2 < 4; ++kk2) {
      bf16x8 pa = *(const bf16x8*)(Pwb + ((kk2 * 64 + lg * 16) ^ pswz));
#pragma unroll
      for (int ni = 0; ni < 4; ++ni) {
        int vrow = ni * 16 + l16;
        bf16x8 vb = *(const bf16x8*)(&Vs[vrow * 128 + (((kk2 * 4 + lg) ^ (vrow & 7)) << 3)]);
        o[ni] = __builtin_amdgcn_mfma_f32_16x16x32_bf16(pa, vb, o[ni], 0, 0, 0);
      }
    }

    asm volatile("s_waitcnt lgkmcnt(0)" ::: "memory");
    __builtin_amdgcn_sched_barrier(0);
    __builtin_amdgcn_s_barrier();
    __builtin_amdgcn_sched_barrier(0);
  }
  storepass(31 * 128);

  float lsj[4];
#pragma unroll
  for (int j = 0; j < 4; ++j) lsj[j] = __shfl(lsum, lg * 4 + j, 64);
#pragma unroll
  for (int ni = 0; ni < 4; ++ni) {
#pragma unroll
    for (int j = 0; j < 4; ++j) {
      size_t row = (size_t)b * 1024 + qrow0 + lg * 4 + j;
      int col = h * 64 + ni * 16 + l16;
      O16[row * 1024 + col] = f2b(o[ni][j] / lsj[j]);
    }
  }
}

extern "C" void kernel_launch(void* const* d_in, const int* in_sizes, int n_in,
                              void* d_out, int out_size, void* d_ws, size_t ws_size,
                              hipStream_t stream) {
  const float* x = (const float*)d_in[0];
  const float* ctx = (const float*)d_in[1];
  const float* dsim = (const float*)d_in[2];
  const int* mask = (const int*)d_in[3];
  const int* cmask = (const int*)d_in[4];
  const float* Wq = (const float*)d_in[5];
  const float* Wkv = (const float*)d_in[6];
  const float* Wout = (const float*)d_in[7];
  const float* bout = (const float*)d_in[8];
  const float* beta = (const float*)d_in[9];

  char* ws = (char*)d_ws;
  u16t* q16 = (u16t*)(ws + (0ull << 20));     //  4 MiB (2048x1024), pre-scaled by d^-0.5
  u16t* k16 = (u16t*)(ws + (4ull << 20));     // 16 MiB (8192x1024) k half, compact
  u16t* vT16 = (u16t*)(ws + (36ull << 20));   // 16 MiB (2,16,64,4096)
  u16t* O16 = (u16t*)(ws + (52ull << 20));    //  4 MiB (2048x1024)
  u16t* x16 = (u16t*)(ws + (56ull << 20));    //  4 MiB
  u16t* ctx16 = (u16t*)(ws + (60ull << 20));  // 16 MiB
  u16t* WqT = (u16t*)(ws + (76ull << 20));    //  2 MiB
  u16t* WkvT = (u16t*)(ws + (78ull << 20));   //  4 MiB
  u16t* WoutT = (u16t*)(ws + (82ull << 20));  //  2 MiB
  unsigned int* cmbits = (unsigned int*)(ws + (84ull << 20)); // 1 KiB

  float* outp = (float*)d_out;
  float* pre = outp + (size_t)2 * 1024 * 1024;

  // fused cvt(x), cvt(ctx), cmask bit-pack, 3x weight transpose
  k_prep<<<11265, 256, 0, stream>>>(x, ctx, x16, ctx16, cmask, cmbits,
                                    Wq, Wkv, Wout, WqT, WkvT, WoutT);
  // combined kv + q GEMM (q fills idle CUs alongside kv)
  k_gemm_qkv<<<1152, 256, 0, stream>>>(x16, WqT, q16, ctx16, WkvT, k16, vT16);
  // fused attention (R11)
  k_attn<<<512, 256, 0, stream>>>(k16, vT16, q16, cmbits, dsim, beta, mask, pre, O16);
  // out = O @ Wout + bout
  k_gemm_out<<<128, 256, 0, stream>>>(O16, WoutT, (float*)d_out, bout);
}

// Round 13
// 214.384 us; speedup vs baseline: 1.6290x; 1.0004x over previous
//
#include <hip/hip_runtime.h>
#include <cstdint>
#include <cstddef>

typedef unsigned short u16t;
typedef __attribute__((ext_vector_type(4))) float f32x4;
typedef __attribute__((ext_vector_type(4))) unsigned int u32x4;
typedef __attribute__((ext_vector_type(8))) __bf16 bf16x8;
typedef __attribute__((ext_vector_type(4))) __bf16 bf16x4;
typedef __attribute__((ext_vector_type(8))) unsigned short u16x8;
typedef __attribute__((ext_vector_type(4))) unsigned short u16x4;

#define INFF __builtin_inff()

__device__ __forceinline__ u16t f2b(float f) {
  union { float f; unsigned u; } x; x.f = f;
  unsigned r = x.u + 0x7FFFu + ((x.u >> 16) & 1u);   // RNE
  return (u16t)(r >> 16);
}

// async global->LDS, 16B per lane. LDS dest = wave-uniform base + lane*16.
__device__ __forceinline__ void gload16(const u16t* g, u16t* l) {
  __builtin_amdgcn_global_load_lds((const __attribute__((address_space(1))) void*)g,
                                   (__attribute__((address_space(3))) void*)l, 16, 0, 0);
}

// ---------------- fused prep: cvt x, cvt ctx, cmask bits, 3x weight transpose ----------------
// blocks [0,2048): x cvt; [2048,10240): ctx cvt; 10240: cmask bit-pack;
// [10241,11265): weight transposes (flattened 64 x 16 grid).
__global__ __launch_bounds__(256) void k_prep(const float* __restrict__ x,
                                              const float* __restrict__ ctx,
                                              u16t* __restrict__ x16,
                                              u16t* __restrict__ ctx16,
                                              const int* __restrict__ cmask,
                                              unsigned int* __restrict__ cmbits,
                                              const float* __restrict__ Wq,
                                              const float* __restrict__ Wkv,
                                              const float* __restrict__ Wout,
                                              u16t* __restrict__ WqT,
                                              u16t* __restrict__ WkvT,
                                              u16t* __restrict__ WoutT) {
  const int bx = blockIdx.x, tid = threadIdx.x;
  if (bx < 2048) {
    int i = bx * 256 + tid;
    f32x4 v = *(const f32x4*)(x + (size_t)i * 4);
    u16x4 o;
    o[0] = f2b(v[0]); o[1] = f2b(v[1]); o[2] = f2b(v[2]); o[3] = f2b(v[3]);
    *(u16x4*)(x16 + (size_t)i * 4) = o;
    return;
  } else if (bx < 10240) {
    int i = (bx - 2048) * 256 + tid;
    f32x4 v = *(const f32x4*)(ctx + (size_t)i * 4);
    u16x4 o;
    o[0] = f2b(v[0]); o[1] = f2b(v[1]); o[2] = f2b(v[2]); o[3] = f2b(v[3]);
    *(u16x4*)(ctx16 + (size_t)i * 4) = o;
    return;
  } else if (bx == 10240) {
    int b = tid >> 7, wdi = tid & 127;
    const int* cp = cmask + b * 4096 + wdi * 32;
    unsigned int bits = 0;
#pragma unroll
    for (int i = 0; i < 32; ++i) bits |= (cp[i] != 0 ? 1u : 0u) << i;
    cmbits[tid] = bits;
    return;
  }
  // weight transpose: id = bx-10241, bxx = id&63 (matrix+col block), by = id>>6 (row block)
  __shared__ float tile[64 * 65];
  const int id = bx - 10241;
  const int bxx = id & 63;
  const float* src; u16t* dst; int C, cb;
  if (bxx < 16)      { src = Wq;   dst = WqT;   C = 1024; cb = bxx * 64; }
  else if (bxx < 48) { src = Wkv;  dst = WkvT;  C = 2048; cb = (bxx - 16) * 64; }
  else               { src = Wout; dst = WoutT; C = 1024; cb = (bxx - 48) * 64; }
  const int rb = (id >> 6) * 64;
#pragma unroll
  for (int it = 0; it < 4; ++it) {
    int c = it * 256 + tid;
    int r = c >> 4, ch = c & 15;
    f32x4 v = *(const f32x4*)(src + (size_t)(rb + r) * C + cb + ch * 4);
    float* dp = &tile[r * 65 + ch * 4];
    dp[0] = v[0]; dp[1] = v[1]; dp[2] = v[2]; dp[3] = v[3];
  }
  __syncthreads();
#pragma unroll
  for (int it = 0; it < 2; ++it) {
    int c = it * 256 + tid;
    int dr = c >> 3, ch = c & 7;
    u16x8 o;
#pragma unroll
    for (int i = 0; i < 8; ++i) o[i] = f2b(tile[(ch * 8 + i) * 65 + dr]);
    *(u16x8*)(dst + (size_t)(cb + dr) * 1024 + rb + ch * 8) = o;
  }
}

// ---------------- GEMM core: C(MxN) = oscale * A(MxK) @ Bt(NxK)^T ----------------
// MODE 0: bf16 C.  MODE 1: f32 C + bias (NT).  MODE 2: kv-dual (k->C direct;
// v-half -> C2=vT via LDS-bounce coalesced transposed store).
template <int MODE>
__device__ __forceinline__ void gemm_body(int g, int per, int nbx,
                                          const u16t* __restrict__ A,
                                          const u16t* __restrict__ Bt,
                                          void* __restrict__ C,
                                          u16t* __restrict__ C2,
                                          const float* __restrict__ bias,
                                          float oscale,
                                          int K, int lda, int ldb, int ldc,
                                          u16t* As, u16t* Bs) {
  const int tid = threadIdx.x;
  const int lane = tid & 63, wid = tid >> 6;
  const int l16 = lane & 15, lg = lane >> 4;
  const int wr = wid >> 1, wc = wid & 1;
  const int w = (g & 7) * per + (g >> 3);       // XCD-aware bijective swizzle
  const int bx = w % nbx, by = w / nbx;
  const int brow = by * 128, bcol = bx * 128;
  const int sr = lane >> 3, chs = lane & 7;
  f32x4 acc[4][4] = {};

  for (int k0 = 0; k0 < K; k0 += 64) {
#pragma unroll
    for (int it = 0; it < 4; ++it) {
      int row = it * 32 + wid * 8 + sr;
      int ch = chs ^ (row & 7);
      gload16(A + (size_t)(brow + row) * lda + k0 + ch * 8, &As[it * 2048 + wid * 512]);
      gload16(Bt + (size_t)(bcol + row) * ldb + k0 + ch * 8, &Bs[it * 2048 + wid * 512]);
    }
    __syncthreads();
#pragma unroll
    for (int kk = 0; kk < 2; ++kk) {
      bf16x8 af[4], bfv[4];
#pragma unroll
      for (int mi = 0; mi < 4; ++mi) {
        int row = wr * 64 + mi * 16 + l16;
        int kch = (kk * 4 + lg) ^ (row & 7);
        af[mi] = *(const bf16x8*)(&As[row * 64 + kch * 8]);
      }
#pragma unroll
      for (int ni = 0; ni < 4; ++ni) {
        int row = wc * 64 + ni * 16 + l16;
        int kch = (kk * 4 + lg) ^ (row & 7);
        bfv[ni] = *(const bf16x8*)(&Bs[row * 64 + kch * 8]);
      }
#pragma unroll
      for (int mi = 0; mi < 4; ++mi)
#pragma unroll
        for (int ni = 0; ni < 4; ++ni)
          acc[mi][ni] = __builtin_amdgcn_mfma_f32_16x16x32_bf16(af[mi], bfv[ni], acc[mi][ni], 0, 0, 0);
    }
    __syncthreads();
  }

  if (MODE == 2 && bcol >= 1024) {
    // v half: bounce through LDS as [vcol 128][pos 128] bf16 (XOR-swizzled),
    // then store vT rows 256B-contiguous (4 segments/instr vs 16 scattered 8B).
    u16t* L = As;  // As+Bs contiguous 32 KB, free after K-loop
#pragma unroll
    for (int ni = 0; ni < 4; ++ni) {
      int vcol = wc * 64 + ni * 16 + l16;
      int swz = (vcol & 7) << 4;
#pragma unroll
      for (int mi = 0; mi < 4; ++mi) {
        int pos0 = wr * 64 + mi * 16 + lg * 4;
        u16x4 pb;
#pragma unroll
        for (int j = 0; j < 4; ++j) pb[j] = f2b(acc[mi][ni][j]);
        *(u16x4*)((char*)L + vcol * 256 + ((pos0 * 2) ^ swz)) = pb;
      }
    }
    __syncthreads();
    const int bb = brow >> 12, basepos = brow & 4095;
#pragma unroll
    for (int p = 0; p < 8; ++p) {
      int o = p * 4096 + tid * 16;
      int r = o >> 8, bix = o & 255;
      u16x8 v = *(const u16x8*)((char*)L + r * 256 + (bix ^ ((r & 7) << 4)));
      int gv = bcol - 1024 + r, h = gv >> 6, hd = gv & 63;
      *(u16x8*)(C2 + ((size_t)((bb * 16 + h) * 64 + hd)) * 4096 + basepos + (bix >> 1)) = v;
    }
    __syncthreads();   // protect L before any later reuse
    return;
  }
#pragma unroll
  for (int mi = 0; mi < 4; ++mi) {
#pragma unroll
    for (int ni = 0; ni < 4; ++ni) {
#pragma unroll
      for (int j = 0; j < 4; ++j) {
        size_t row = (size_t)brow + wr * 64 + mi * 16 + lg * 4 + j;
        int col = bcol + wc * 64 + ni * 16 + l16;
        float v = acc[mi][ni][j] * oscale;
        if (MODE == 1) {
          v += bias[col];
          __builtin_nontemporal_store(v, (float*)C + row * ldc + col);
        } else {
          ((u16t*)C)[row * ldc + col] = f2b(v);
        }
      }
    }
  }
}

// combined q + kv GEMM: blocks [0,1024) = kv (MODE2), [1024,1152) = q (MODE0).
__global__ __launch_bounds__(256) void k_gemm_qkv(const u16t* __restrict__ x16,
                                                  const u16t* __restrict__ WqT,
                                                  u16t* __restrict__ q16,
                                                  const u16t* __restrict__ ctx16,
                                                  const u16t* __restrict__ WkvT,
                                                  u16t* __restrict__ k16,
                                                  u16t* __restrict__ vT16) {
  __shared__ u16t smem[2 * 128 * 64];
  u16t* As = smem;
  u16t* Bs = smem + 128 * 64;
  if (blockIdx.x < 1024)
    gemm_body<2>(blockIdx.x, 128, 16, ctx16, WkvT, (void*)k16, vT16, nullptr, 1.0f,
                 1024, 1024, 1024, 1024, As, Bs);
  else
    gemm_body<0>(blockIdx.x - 1024, 16, 8, x16, WqT, (void*)q16, nullptr, nullptr, 0.03125f,
                 1024, 1024, 1024, 1024, As, Bs);
}

// out = O @ Wout + bout (f32, NT)
__global__ __launch_bounds__(256) void k_gemm_out(const u16t* __restrict__ O16,
                                                  const u16t* __restrict__ WoutT,
                                                  float* __restrict__ out,
                                                  const float* __restrict__ bout) {
  __shared__ u16t smem[2 * 128 * 64];
  gemm_body<1>(blockIdx.x, 16, 8, O16, WoutT, (void*)out, nullptr, bout, 1.0f,
               1024, 1024, 1024, 1024, smem, smem + 128 * 64);
}

// ---------------- fused attention (R11, unchanged) ----------------
__global__ __launch_bounds__(256) void k_attn(const u16t* __restrict__ k16,
                                              const u16t* __restrict__ vT16,
                                              const u16t* __restrict__ q16,
                                              const unsigned int* __restrict__ cmbits,
                                              const float* __restrict__ dsim,
                                              const float* __restrict__ beta_p,
                                              const int* __restrict__ mask,
                                              float* __restrict__ pre,
                                              u16t* __restrict__ O16) {
  __shared__ u16t Ks[128 * 64];    // [kv 128][hd 64] swizzled, 16 KB
  __shared__ u16t Vs[64 * 128];    // [hd 64][kv 128] swizzled, 16 KB
  __shared__ u16t Ps[4 * 2048];    // per-wave P [16 q][128 kv] bf16, 16 KB
  __shared__ float Sf[4 * 2048];   // per-wave raw S [16 q][128 kv] f32, 32 KB

  const int tid = threadIdx.x;
  const int lane = tid & 63, wid = tid >> 6;
  const int l16 = lane & 15, lg = lane >> 4;
  const int g = blockIdx.x;
  const int w = (g & 7) * 64 + (g >> 3);
  const int nb = w & 15, hb = w >> 4;
  const int h = hb & 15, b = hb >> 4;
  const int qrow0 = nb * 64 + wid * 16;

  bf16x8 aq0, aq1;
  {
    const u16t* qp = q16 + (size_t)(b * 1024 + qrow0 + l16) * 1024 + h * 64 + lg * 8;
    aq0 = *(const bf16x8*)(qp);
    aq1 = *(const bf16x8*)(qp + 32);
  }
  const bool qm = mask[b * 1024 + qrow0 + l16] != 0;

  const float beta = beta_p[0];
  const float ds40 = dsim[b * 4 + 0] * beta, ds41 = dsim[b * 4 + 1] * beta;
  const float ds42 = dsim[b * 4 + 2] * beta, ds43 = dsim[b * 4 + 3] * beta;

  float mrow = -INFF, lsum = 0.f;
  f32x4 o[4] = {};

  const u16t* kbase = k16 + (size_t)b * 4096 * 1024 + (size_t)h * 64;
  const u16t* vbase = vT16 + (size_t)(b * 16 + h) * 64 * 4096;
  float* preb = pre + (size_t)((b * 16 + h) * 1024 + qrow0) * 4096;
  const u32x4* cmw = (const u32x4*)(cmbits + b * 128);
  char* Pwb = (char*)&Ps[wid * 2048] + l16 * 256;
  const int pswz = (l16 & 7) << 4;
  char* Swave = (char*)&Sf[wid * 2048];
  char* Swb = Swave + l16 * 512;

  auto stage = [&](int kv0s) {
    u16t* Kb = &Ks[wid * 2048];
    u16t* Vb = &Vs[wid * 2048];
#pragma unroll
    for (int it = 0; it < 4; ++it) {
      int row = wid * 32 + it * 8 + (lane >> 3);
      int ch = (lane & 7) ^ (row & 7);
      gload16(kbase + (size_t)(kv0s + row) * 1024 + ch * 8, Kb + it * 512);
    }
#pragma unroll
    for (int it = 0; it < 4; ++it) {
      int row = wid * 16 + it * 4 + (lane >> 4);
      int ch = (lane & 15) ^ (row & 7);
      gload16(vbase + (size_t)row * 4096 + kv0s + ch * 8, Vb + it * 512);
    }
  };

  auto storepass = [&](int kv0p) {
    const int rhalf = lane >> 5, c4 = (lane & 31) * 4;
#pragma unroll
    for (int i = 0; i < 8; ++i) {
      const int row2 = i * 2 + rhalf;
      f32x4 v = *(const f32x4*)(Swave + row2 * 512 + ((c4 * 4) ^ ((row2 & 7) << 4)));
      __builtin_nontemporal_store(v, (f32x4*)(preb + (size_t)row2 * 4096 + kv0p + c4));
    }
  };

  for (int t = 0; t < 32; ++t) {
    const u32x4 Wc = cmw[t];
    stage(t * 128);
    asm volatile("" ::: "memory");
    if (t > 0) storepass((t - 1) * 128);
    if (t == 0) {
      asm volatile("s_waitcnt vmcnt(0) lgkmcnt(0)" ::: "memory");
    } else {
      asm volatile("s_waitcnt vmcnt(8) lgkmcnt(0)" ::: "memory");
    }
    __builtin_amdgcn_sched_barrier(0);
    __builtin_amdgcn_s_barrier();
    __builtin_amdgcn_sched_barrier(0);

    const int kv0 = t * 128;
    const int d = t >> 3;
    const float ds_t = (d & 1) ? ((d & 2) ? ds43 : ds41) : ((d & 2) ? ds42 : ds40);

    f32x4 s[8];
#pragma unroll
    for (int kb = 0; kb < 8; ++kb) {
      f32x4 acc = {0.f, 0.f, 0.f, 0.f};
      int row = kb * 16 + l16;
      bf16x8 bk0 = *(const bf16x8*)(&Ks[row * 64 + ((lg ^ (row & 7)) << 3)]);
      bf16x8 bk1 = *(const bf16x8*)(&Ks[row * 64 + (((4 + lg) ^ (row & 7)) << 3)]);
      acc = __builtin_amdgcn_mfma_f32_16x16x32_bf16(bk0, aq0, acc, 0, 0, 0);
      acc = __builtin_amdgcn_mfma_f32_16x16x32_bf16(bk1, aq1, acc, 0, 0, 0);
      s[kb] = acc;
    }

    float tmax = -INFF;
#pragma unroll
    for (int kb = 0; kb < 8; ++kb) {
      *(f32x4*)(Swb + ((kb * 64 + lg * 16) ^ pswz)) = s[kb];
      const unsigned int sh = Wc[kb >> 1] >> ((kb & 1) * 16 + lg * 4);
#pragma unroll
      for (int j = 0; j < 4; ++j) {
        float bias = ((sh >> j) & 1u) ? ds_t : -INFF;
        float t2 = s[kb][j] + bias;
        if (!qm) t2 = 0.f;
        if (t2 == 0.f) t2 = -INFF;
        s[kb][j] = t2;
        tmax = fmaxf(tmax, t2);
      }
    }
    tmax = fmaxf(tmax, __shfl_xor(tmax, 16, 64));
    tmax = fmaxf(tmax, __shfl_xor(tmax, 32, 64));
    const float mold = mrow;
    const float mn = fmaxf(mold, tmax);
    const bool nochange = __all(mn == mold);
    mrow = mn;

    float psum = 0.f;
#pragma unroll
    for (int kb = 0; kb < 8; ++kb) {
      bf16x4 pb;
#pragma unroll
      for (int j = 0; j < 4; ++j) {
        float p = (mn == -INFF) ? 0.f : __expf(s[kb][j] - mn);
        psum += p;
        pb[j] = (__bf16)p;
      }
      *(bf16x4*)(Pwb + ((kb * 32 + lg * 8) ^ pswz)) = pb;
    }
    asm volatile("" ::: "memory");
    psum += __shfl_xor(psum, 16, 64);
    psum += __shfl_xor(psum, 32, 64);

    if (nochange) {
      lsum += psum;
    } else {
      const float fs = (mn == -INFF) ? 0.f : __expf(mold - mn);
      lsum = lsum * fs + psum;
      float fsj[4];
#pragma unroll
      for (int j = 0; j < 4; ++j) fsj[j] = __shfl(fs, lg * 4 + j, 64);
#pragma unroll
      for (int ni = 0; ni < 4; ++ni)
#pragma unroll
        for (int j = 0; j < 4; ++j) o[ni][j] *= fsj[j];
    }

#pragma unroll
    for (int kk2 = 0; kk2 < 4; ++kk2) {
      bf16x8 pa = *(const bf16x8*)(Pwb + ((kk2 * 64 + lg * 16) ^ pswz));
#pragma unroll
      for (int ni = 0; ni < 4; ++ni) {
        int vrow = ni * 16 + l16;
        bf16x8 vb = *(const bf16x8*)(&Vs[vrow * 128 + (((kk2 * 4 + lg) ^ (vrow & 7)) << 3)]);
        o[ni] = __builtin_amdgcn_mfma_f32_16x16x32_bf16(pa, vb, o[ni], 0, 0, 0);
      }
    }

    asm volatile("s_waitcnt lgkmcnt(0)" ::: "memory");
    __builtin_amdgcn_sched_barrier(0);
    __builtin_amdgcn_s_barrier();
    __builtin_amdgcn_sched_barrier(0);
  }
  storepass(31 * 128);

  float lsj[4];
#pragma unroll
  for (int j = 0; j < 4; ++j) lsj[j] = __shfl(lsum, lg * 4 + j, 64);
#pragma unroll
  for (int ni = 0; ni < 4; ++ni) {
#pragma unroll
    for (int j = 0; j < 4; ++j) {
      size_t row = (size_t)b * 1024 + qrow0 + lg * 4 + j;
      int col = h * 64 + ni * 16 + l16;
      O16[row * 1024 + col] = f2b(o[ni][j] / lsj[j]);
    }
  }
}

extern "C" void kernel_launch(void* const* d_in, const int* in_sizes, int n_in,
                              void* d_out, int out_size, void* d_ws, size_t ws_size,
                              hipStream_t stream) {
  const float* x = (const float*)d_in[0];
  const float* ctx = (const float*)d_in[1];
  const float* dsim = (const float*)d_in[2];
  const int* mask = (const int*)d_in[3];
  const int* cmask = (const int*)d_in[4];
  const float* Wq = (const float*)d_in[5];
  const float* Wkv = (const float*)d_in[6];
  const float* Wout = (const float*)d_in[7];
  const float* bout = (const float*)d_in[8];
  const float* beta = (const float*)d_in[9];

  char* ws = (char*)d_ws;
  u16t* q16 = (u16t*)(ws + (0ull << 20));     //  4 MiB (2048x1024), pre-scaled by d^-0.5
  u16t* k16 = (u16t*)(ws + (4ull << 20));     // 16 MiB (8192x1024) k half, compact
  u16t* vT16 = (u16t*)(ws + (36ull << 20));   // 16 MiB (2,16,64,4096)
  u16t* O16 = (u16t*)(ws + (52ull << 20));    //  4 MiB (2048x1024)
  u16t* x16 = (u16t*)(ws + (56ull << 20));    //  4 MiB
  u16t* ctx16 = (u16t*)(ws + (60ull << 20));  // 16 MiB
  u16t* WqT = (u16t*)(ws + (76ull << 20));    //  2 MiB
  u16t* WkvT = (u16t*)(ws + (78ull << 20));   //  4 MiB
  u16t* WoutT = (u16t*)(ws + (82ull << 20));  //  2 MiB
  unsigned int* cmbits = (unsigned int*)(ws + (84ull << 20)); // 1 KiB

  float* outp = (float*)d_out;
  float* pre = outp + (size_t)2 * 1024 * 1024;

  // fused cvt(x), cvt(ctx), cmask bit-pack, 3x weight transpose
  k_prep<<<11265, 256, 0, stream>>>(x, ctx, x16, ctx16, cmask, cmbits,
                                    Wq, Wkv, Wout, WqT, WkvT, WoutT);
  // combined kv + q GEMM (q fills idle CUs alongside kv)
  k_gemm_qkv<<<1152, 256, 0, stream>>>(x16, WqT, q16, ctx16, WkvT, k16, vT16);
  // fused attention (R11)
  k_attn<<<512, 256, 0, stream>>>(k16, vT16, q16, cmbits, dsim, beta, mask, pre, O16);
  // out = O @ Wout + bout
  k_gemm_out<<<128, 256, 0, stream>>>(O16, WoutT, (float*)d_out, bout);
}